// Round 12
// baseline (166.180 us; speedup 1.0000x reference)
//
#include <hip/hip_runtime.h>

// Residual VQ (L=4, K=4096, C=256, N=4096) — bf16 screen + exact-candidate refine.
// Round-8 gemm config (128x128, 4 blocks/CU). Wave-per-row refine (grid 1024).
// Deterministic per-slice candidate slots: cand/cval[n][bn*16+j], count byte
// cslc[n][bn] (255 = overflow). NO global atomics anywhere in the hot path.
// Screen error bound eps = 0.004*||r||; margin M = 0.012*||r|| >= 3*eps.
// Overflow paths degrade deterministically to full exact scan (wave-serial).

// ws layout (float units):
#define OFF_AS   0          // N x 256 bf16      = 524288 floats
#define OFF_BS   524288     // L*K x 256 bf16    = 2097152 floats
#define OFF_R    2621440    // N x C fp32        = 1048576
#define OFF_INV  3670016    // L x K             = 16384
#define OFF_CSLC 3686400    // N x 32 uchar      = 32768 floats
#define OFF_CAND 3719168    // N x 512 (int)     = 2097152
#define OFF_CVAL 5816320    // N x 512           = 2097152
#define OFF_SSQ  7913472    // L x N             = 16384
// total 7929856 floats ~ 31.7 MB

#define BETA 0.25f
#define EPSN 1e-12f
#define SLC 16              // candidate slots per row per 128-col slice
#define MARGIN 0.012f
#define NEGINF -3.0e38f

typedef __attribute__((ext_vector_type(8))) short short8;
typedef __attribute__((ext_vector_type(4))) short short4v;
typedef __attribute__((ext_vector_type(4))) float f32x4;

__device__ __forceinline__ unsigned short f2bf(float x) {
  unsigned u = __float_as_uint(x);
  unsigned r = (u + 0x7fffu + ((u >> 16) & 1u)) >> 16;
  return (unsigned short)r;
}

__device__ __forceinline__ void gload16(const void* g, void* s) {
  __builtin_amdgcn_global_load_lds(
      (const __attribute__((address_space(1))) unsigned int*)g,
      (__attribute__((address_space(3))) unsigned int*)s, 16, 0, 0);
}

// ---- merged prep: blocks 0..2047 codebook (norm + bf16 B); 2048..2559 rows ----
__global__ __launch_bounds__(256) void k_prep(const float* __restrict__ z,
                                              const float* __restrict__ cb,
                                              float* __restrict__ r,
                                              unsigned short* __restrict__ AS,
                                              float* __restrict__ rnorm,
                                              float* __restrict__ inv,
                                              unsigned short* __restrict__ BS) {
  __shared__ __align__(16) char psm[9472];
  int tid = threadIdx.x;
  int w = tid >> 6, lane = tid & 63;
  if (blockIdx.x < 2048) {
    // ---- codebook part: 8 rows per block ----
    float (*t)[260] = (float(*)[260])psm;
    float* sinvs = (float*)(psm + 8320);
    int r0 = blockIdx.x * 8;
#pragma unroll
    for (int p = 0; p < 2; ++p) {
      int idx = p * 1024 + tid * 4;
      float4 v = *(const float4*)(cb + (size_t)r0 * 256 + idx);
      int row = idx >> 8, c = idx & 255;
      *(float4*)&t[row][c] = v;
    }
    __syncthreads();
#pragma unroll
    for (int rr = 0; rr < 2; ++rr) {
      int row = w * 2 + rr;
      float4 v = *(const float4*)&t[row][lane * 4];
      float s = v.x * v.x + v.y * v.y + v.z * v.z + v.w * v.w;
#pragma unroll
      for (int off = 32; off; off >>= 1) s += __shfl_xor(s, off);
      if (lane == 0) sinvs[row] = 1.0f / fmaxf(sqrtf(s), EPSN);
    }
    __syncthreads();
    if (tid < 8) inv[r0 + tid] = sinvs[tid];
#pragma unroll
    for (int p = 0; p < 2; ++p) {
      int idx = p * 1024 + tid * 4;
      int row = idx >> 8, c = idx & 255;
      float sc = sinvs[row];
      short4v s4;
      s4[0] = (short)f2bf(t[row][c + 0] * sc);
      s4[1] = (short)f2bf(t[row][c + 1] * sc);
      s4[2] = (short)f2bf(t[row][c + 2] * sc);
      s4[3] = (short)f2bf(t[row][c + 3] * sc);
      *(short4v*)(BS + (size_t)r0 * 256 + idx) = s4;
    }
  } else {
    // ---- rows part: transpose z -> r + bf16 A + norms ----
    float (*t)[9] = (float(*)[9])psm;
    float* wpart = (float*)(psm + 9216);   // [4][8]
    int n0 = (blockIdx.x - 2048) * 8;
    int b = n0 >> 10, hw0 = n0 & 1023;
#pragma unroll
    for (int p = 0; p < 8; ++p) {
      int c = p * 32 + (tid >> 3), h = tid & 7;
      t[c][h] = z[((b * 256 + c) << 10) + hw0 + h];
    }
    __syncthreads();
#pragma unroll
    for (int h = 0; h < 8; ++h) {
      float v = t[tid][h];
      float s = v * v;
#pragma unroll
      for (int off = 32; off; off >>= 1) s += __shfl_xor(s, off);
      if (lane == 0) wpart[w * 8 + h] = s;
    }
    __syncthreads();
    if (tid < 8) {
      float tot = (wpart[0 * 8 + tid] + wpart[1 * 8 + tid]) +
                  (wpart[2 * 8 + tid] + wpart[3 * 8 + tid]);
      rnorm[n0 + tid] = sqrtf(tot);
    }
#pragma unroll
    for (int h = 0; h < 8; ++h) {
      float v = t[tid][h];
      r[(n0 + h) * 256 + tid] = v;
      AS[(n0 + h) * 256 + tid] = f2bf(v);
    }
  }
}

// ---- bf16 screen GEMM (128x128 tile) + slice max + deterministic slots ----
// Epilogue LDS aliased onto lA/lB (dead after K-loop): total 32.8 KB.
__global__ __launch_bounds__(256) void k_gemm_argmax(
    const unsigned short* __restrict__ AS, const unsigned short* __restrict__ BS,
    const float* __restrict__ rnorm, unsigned char* __restrict__ cslc,
    int* __restrict__ cand, float* __restrict__ cval) {
  __shared__ __align__(16) char sm[32768];
  unsigned short* lA = (unsigned short*)sm;             // 16384 B (K-loop)
  unsigned short* lB = (unsigned short*)(sm + 16384);   // 16384 B (K-loop)
  float* sv    = (float*)sm;                            // [4][64] 1024 B (epilogue)
  float* scomb = (float*)(sm + 1024);                   // [2][64] 512 B
  float* rn_s  = (float*)(sm + 1536);                   // 512 B
  int*   lcnt  = (int*)(sm + 2048);                     // 512 B
  int*   lck   = (int*)(sm + 2560);                     // [128][SLC] 8192 B
  float* lcv   = (float*)(sm + 10752);                  // 8192 B (ends 18944)

  int bid = blockIdx.x;
  int wg = (bid & 7) * 128 + (bid >> 3);   // XCD swizzle (1024 % 8 == 0)
  int bm = wg >> 5, bn = wg & 31;
  int mbase = bm * 128, nbase = bn * 128;
  int tid = threadIdx.x;
  int wid = tid >> 6, ln = tid & 63;
  int wr = wid >> 1, wc = wid & 1;
  int grp = ln >> 4, li = ln & 15;

  f32x4 acc[4][4];
#pragma unroll
  for (int i = 0; i < 4; ++i)
#pragma unroll
    for (int j = 0; j < 4; ++j) acc[i][j] = (f32x4){0.f, 0.f, 0.f, 0.f};

  for (int ks = 0; ks < 4; ++ks) {
    __syncthreads();
    int k0 = ks * 64;
#pragma unroll
    for (int i = 0; i < 4; ++i) {
      int idx = i * 256 + tid;
      int row = idx >> 3, cc = idx & 7;
      int src = cc ^ (row & 7);
      gload16(AS + ((mbase + row) << 8) + k0 + src * 8, ((char*)lA) + idx * 16);
    }
#pragma unroll
    for (int i = 0; i < 4; ++i) {
      int idx = i * 256 + tid;
      int row = idx >> 3, cc = idx & 7;
      int src = cc ^ (row & 7);
      gload16(BS + ((nbase + row) << 8) + k0 + src * 8, ((char*)lB) + idx * 16);
    }
    __syncthreads();
#pragma unroll
    for (int kk = 0; kk < 2; ++kk) {
      short8 b[4];
#pragma unroll
      for (int ni = 0; ni < 4; ++ni) {
        int row = wc * 64 + ni * 16 + li;
        int cc = kk * 4 + grp;
        b[ni] = *(const short8*)(((const char*)lB) + row * 128 + (cc ^ (row & 7)) * 16);
      }
#pragma unroll
      for (int mi = 0; mi < 4; ++mi) {
        int row = wr * 64 + mi * 16 + li;
        int cc = kk * 4 + grp;
        short8 a = *(const short8*)(((const char*)lA) + row * 128 + (cc ^ (row & 7)) * 16);
#pragma unroll
        for (int ni = 0; ni < 4; ++ni)
          acc[mi][ni] = __builtin_amdgcn_mfma_f32_16x16x32_bf16(a, b[ni], acc[mi][ni], 0, 0, 0);
      }
    }
  }

  // per-wave 64-col slice max per row — into registers first (LDS still = tiles)
  float redv[4][4];
#pragma unroll
  for (int mi = 0; mi < 4; ++mi) {
#pragma unroll
    for (int reg = 0; reg < 4; ++reg) {
      float v = acc[mi][0][reg];
#pragma unroll
      for (int ni = 1; ni < 4; ++ni) v = fmaxf(v, acc[mi][ni][reg]);
#pragma unroll
      for (int off = 1; off < 16; off <<= 1) v = fmaxf(v, __shfl_xor(v, off));
      redv[mi][reg] = v;
    }
  }
  __syncthreads();   // all tile reads done -> safe to alias epilogue arrays
#pragma unroll
  for (int mi = 0; mi < 4; ++mi)
#pragma unroll
    for (int reg = 0; reg < 4; ++reg)
      if (li == 0) sv[(wr * 2 + wc) * 64 + mi * 16 + grp * 4 + reg] = redv[mi][reg];
  __syncthreads();
  if (tid < 128) {
    int wr2 = tid >> 6, r64 = tid & 63;
    float m = fmaxf(sv[(wr2 * 2 + 0) * 64 + r64], sv[(wr2 * 2 + 1) * 64 + r64]);
    int n = mbase + wr2 * 64 + r64;
    scomb[wr2 * 64 + r64] = m;
    rn_s[wr2 * 64 + r64] = rnorm[n];
    lcnt[tid] = 0;
  }
  __syncthreads();
  // candidate collection into per-row LDS buffers (LDS atomics only)
#pragma unroll
  for (int mi = 0; mi < 4; ++mi) {
#pragma unroll
    for (int reg = 0; reg < 4; ++reg) {
      int rl = mi * 16 + grp * 4 + reg;
      float thr = scomb[wr * 64 + rl] - MARGIN * rn_s[wr * 64 + rl];
      int rloc = wr * 64 + rl;
#pragma unroll
      for (int ni = 0; ni < 4; ++ni) {
        float v = acc[mi][ni][reg];
        if (v >= thr) {
          int pos = atomicAdd(&lcnt[rloc], 1);
          if (pos < SLC) {
            lck[rloc * SLC + pos] = nbase + wc * 64 + ni * 16 + li;
            lcv[rloc * SLC + pos] = v;
          }
        }
      }
    }
  }
  __syncthreads();
  // write-out: deterministic slots, pure stores (no global atomics)
  if (tid < 128) {
    int rloc = tid;
    int n = mbase + rloc;
    int raw = lcnt[rloc];
    int lc = raw < SLC ? raw : SLC;
    cslc[(n << 5) + bn] = (unsigned char)(raw > SLC ? 255 : lc);
    int base = (n << 9) + bn * SLC;
    for (int j = 0; j < lc; ++j) {
      cand[base + j] = lck[rloc * SLC + j];
      cval[base + j] = lcv[rloc * SLC + j];
    }
  }
}

// ---- wave-per-row refine: gmax from stored slice maxes -> filter -> exact dots
//      -> residual update + next A split. Grid 1024, 4 rows/block, NO barriers.
__global__ __launch_bounds__(256) void k_refine_update(
    const float* __restrict__ cb, const float* __restrict__ inv,
    float* __restrict__ r, float* __restrict__ rnorm,
    const unsigned char* __restrict__ cslc,
    const int* __restrict__ cand, const float* __restrict__ cval,
    unsigned short* __restrict__ AS, float* __restrict__ ssq,
    float* __restrict__ out_idx, int l) {
  __shared__ int lists[4][128];
  __shared__ int lcnts[4];
  int tid = threadIdx.x, w = tid >> 6, lane = tid & 63;
  int n = blockIdx.x * 4 + w;
  const float* cbl = cb + ((size_t)l << 20);
  const float* invl = inv + (l << 12);

  float4 rv4 = *(const float4*)(r + ((size_t)n << 8) + lane * 4);

  // lane L covers slots [(L>>1)*16 + (L&1)*8, +8) of its row's 512-slot space
  int cnt_l = cslc[(n << 5) + (lane >> 1)];
  bool ovf = __any(cnt_l == 255);
  int sbase = (n << 9) + (lane >> 1) * 16 + (lane & 1) * 8;
  int4 k0 = *(const int4*)(cand + sbase);
  int4 k1 = *(const int4*)(cand + sbase + 4);
  float4 v0 = *(const float4*)(cval + sbase);
  float4 v1 = *(const float4*)(cval + sbase + 4);
  int nvalid = cnt_l - ((lane & 1) << 3);
  nvalid = nvalid < 0 ? 0 : (nvalid > 8 ? 8 : nvalid);
  float vv[8] = {v0.x, v0.y, v0.z, v0.w, v1.x, v1.y, v1.z, v1.w};
  int   kk[8] = {k0.x, k0.y, k0.z, k0.w, k1.x, k1.y, k1.z, k1.w};

  // global screened max = max over stored slice maxes (slice max is always stored)
  float gm = NEGINF;
#pragma unroll
  for (int j = 0; j < 8; ++j) if (j < nvalid) gm = fmaxf(gm, vv[j]);
#pragma unroll
  for (int off = 32; off; off >>= 1) gm = fmaxf(gm, __shfl_xor(gm, off));

  float bv = NEGINF; int bk = 0x7fffffff;
  bool full = ovf;
  if (!ovf) {
    float thr = gm - MARGIN * rnorm[n];
    if (lane == 0) lcnts[w] = 0;   // per-wave LDS, in-order DS pipeline
#pragma unroll
    for (int j = 0; j < 8; ++j) {
      if (j < nvalid && vv[j] >= thr) {
        int p = atomicAdd(&lcnts[w], 1);
        if (p < 128) lists[w][p] = kk[j];
      }
    }
    int m = lcnts[w];              // same-wave DS ordering guarantees visibility
    if (m <= 128) {
      for (int j = 0; j < m; ++j) {
        int k = lists[w][j];
        float4 e4 = *(const float4*)(cbl + ((size_t)k << 8) + lane * 4);
        float p = rv4.x * e4.x + rv4.y * e4.y + rv4.z * e4.z + rv4.w * e4.w;
#pragma unroll
        for (int off = 32; off; off >>= 1) p += __shfl_xor(p, off);
        float s = p * invl[k];     // uniform across lanes
        if (s > bv || (s == bv && k < bk)) { bv = s; bk = k; }
      }
    } else full = true;
  }
  if (full) {
    // overflow fallback (~never): wave-serial full exact scan
    bv = NEGINF; bk = 0x7fffffff;
    for (int k = 0; k < 4096; ++k) {
      float4 e4 = *(const float4*)(cbl + ((size_t)k << 8) + lane * 4);
      float p = rv4.x * e4.x + rv4.y * e4.y + rv4.z * e4.z + rv4.w * e4.w;
#pragma unroll
      for (int off = 32; off; off >>= 1) p += __shfl_xor(p, off);
      float s = p * invl[k];
      if (s > bv || (s == bv && k < bk)) { bv = s; bk = k; }
    }
  }
  if (lane == 0) out_idx[(l << 12) + n] = (float)bk;

  // residual update + next-level A split (AS/rnorm dead at l==3)
  float4 e4 = *(const float4*)(cbl + ((size_t)bk << 8) + lane * 4);
  float4 nv = {rv4.x - e4.x, rv4.y - e4.y, rv4.z - e4.z, rv4.w - e4.w};
  *(float4*)(r + ((size_t)n << 8) + lane * 4) = nv;
  if (l != 3) {
    short4v s4;
    s4[0] = (short)f2bf(nv.x); s4[1] = (short)f2bf(nv.y);
    s4[2] = (short)f2bf(nv.z); s4[3] = (short)f2bf(nv.w);
    *(short4v*)(AS + ((size_t)n << 8) + lane * 4) = s4;
  }
  float sq = nv.x * nv.x + nv.y * nv.y + nv.z * nv.z + nv.w * nv.w;
#pragma unroll
  for (int off = 32; off; off >>= 1) sq += __shfl_xor(sq, off);
  if (lane == 0) {
    ssq[(l << 12) + n] = sq;
    if (l != 3) rnorm[n] = sqrtf(sq);
  }
}

// ---- z_q_st = z - residual_final (blocks 0..1023); qloss (block 1024) ----
__global__ __launch_bounds__(256) void k_writeq_qloss(const float* __restrict__ z,
                                                      const float* __restrict__ r,
                                                      const float* __restrict__ ssq,
                                                      float* __restrict__ out) {
  int tid = threadIdx.x;
  if (blockIdx.x == 1024) {
    __shared__ float wsumq[4];
    float q = 0.f;
    for (int l = 0; l < 4; ++l) {
      float p = 0.f;
#pragma unroll
      for (int i = 0; i < 16; ++i) p += ssq[l * 4096 + i * 256 + tid];
      int lane = tid & 63, w = tid >> 6;
#pragma unroll
      for (int off = 32; off; off >>= 1) p += __shfl_xor(p, off);
      if (lane == 0) wsumq[w] = p;
      __syncthreads();
      float tot = (wsumq[0] + wsumq[1]) + (wsumq[2] + wsumq[3]);
      q += BETA * (tot * (1.0f / (4096.0f * 256.0f)));
      __syncthreads();
    }
    if (tid == 0) out[1048576 + 16384] = q;
    return;
  }
  __shared__ float t[32][33];
  int id = blockIdx.x;
  int b = id >> 8; int rem = id & 255; int ct = rem >> 5; int ht = rem & 31;
  int c0 = ct * 32, h0 = ht * 32;
  int col = tid & 31, row0 = tid >> 5;
#pragma unroll
  for (int p = 0; p < 4; ++p) {
    int row = row0 + p * 8;
    t[row][col] = r[(b * 1024 + h0 + row) * 256 + c0 + col];
  }
  __syncthreads();
#pragma unroll
  for (int p = 0; p < 4; ++p) {
    int row = row0 + p * 8;
    int o = ((b * 256 + c0 + row) << 10) + h0 + col;
    out[o] = z[o] - t[col][row];
  }
}

extern "C" void kernel_launch(void* const* d_in, const int* in_sizes, int n_in,
                              void* d_out, int out_size, void* d_ws, size_t ws_size,
                              hipStream_t stream) {
  const float* z  = (const float*)d_in[0];
  const float* cb = (const float*)d_in[1];
  float* out = (float*)d_out;
  float* ws  = (float*)d_ws;

  unsigned short* AS = (unsigned short*)(ws + OFF_AS);
  unsigned short* BS = (unsigned short*)(ws + OFF_BS);
  float* r     = ws + OFF_R;
  float* inv   = ws + OFF_INV;
  unsigned char* cslc = (unsigned char*)(ws + OFF_CSLC);
  int*   cand  = (int*)(ws + OFF_CAND);
  float* cval  = ws + OFF_CVAL;
  float* ssq   = ws + OFF_SSQ;
  float* rnorm = ws + OFF_SSQ + 16384;   // reuse tail: N floats right after ssq

  k_prep<<<2560, 256, 0, stream>>>(z, cb, r, AS, rnorm, inv, BS);
  for (int l = 0; l < 4; ++l) {
    k_gemm_argmax<<<1024, 256, 0, stream>>>(AS, BS + (size_t)l * 4096 * 256,
                                            rnorm, cslc, cand, cval);
    k_refine_update<<<1024, 256, 0, stream>>>(cb, inv, r, rnorm, cslc,
                                              cand, cval, AS, ssq,
                                              out + 1048576, l);
  }
  k_writeq_qloss<<<1025, 256, 0, stream>>>(z, r, ssq, out);
}